// Round 4
// baseline (266.773 us; speedup 1.0000x reference)
//
#include <hip/hip_runtime.h>

// PopulationODE: explicit Euler, L=512, B=32768, 4 states, 21 weights.
// Output [L,4,B] fp32 = 256 MiB -> write-bound (harness fill: 6.6 TB/s).
//
// History (kernel-only time = dur_us - ~163us harness fill):
//   R0 single-pass, 2 waves/CU:            ~110 us (per-step store-ack stall)
//   R1 checkpoint+segment split:           ~126 us (serialized dispatches)
//   R2 segment-parallel redundant compute: ~141 us (8.5x VALU redundancy)
//   R3 reg-staging pipe, 2 waves/CU:       ~102 us (store pipe still too
//       shallow: a lone wave per 2 SIMDs can't keep enough stores in flight)
// R4: producer/consumer waves in ONE dispatch, zero redundancy.
//   Block = 320 threads: wave 0 computes 64 trajectories (registers only,
//   never waits on vmcnt); waves 1..4 each own one state row and stream
//   LDS -> global. Double-buffered LDS group of G=8 rows; sync via
//   s_waitcnt lgkmcnt(0) + raw s_barrier (T3 pattern) so writer stores
//   pipeline ACROSS groups (no vmcnt(0) drain as __syncthreads would emit).
//   512 blocks -> 10 waves/CU; writer side is a pure streaming copy.
// Floor: 256 MiB / 6.6 TB/s = 41 us writes; compute path ~800cy/group < the
// ~1530cy/group BW share -> hidden.

#define ODE_L 512
#define ODE_B 32768
#define G     8                  // rows per LDS group
#define NGRP  64                 // groups 0..62 full, group 63 has 7 rows
#define TPB   320                // 1 compute wave + 4 writer waves

// One Euler step (bit-identical op order to the verified R0/R3 kernels).
#define ODE_STEP(h)                                                          \
  do {                                                                       \
    const float dA = w0  + w1  * A + w2  * A * A;                            \
    const float dT = w3  + w4  * T + w5  * T * T + w6  * A + w7  * A * A +   \
                     w8  * A * T;                                            \
    const float dN = w9  + w10 * N + w11 * N * N + w12 * T + w13 * T * T +   \
                     w14 * T * N;                                            \
    const float dC = w15 + w16 * C + w17 * C * C + w18 * N + w19 * N * N +   \
                     w20 * N * C;                                            \
    A += h * dA; T += h * dT; N += h * dN; C += h * dC;                      \
  } while (0)

// LDS-only barrier: drain DS ops, do NOT drain vmcnt (stores stay in flight).
__device__ __forceinline__ void sync_lds() {
    asm volatile("s_waitcnt lgkmcnt(0)" ::: "memory");
    __builtin_amdgcn_s_barrier();
}

__global__ __launch_bounds__(TPB) void population_ode_kernel(
    const float* __restrict__ s_grid,   // [L]
    const float* __restrict__ y0,       // [4, B]
    const float* __restrict__ w,        // [21]
    float* __restrict__ out)            // [L, 4, B]
{
    __shared__ float sh_h[ODE_L - 1];        // h[i] = s[i+1] - s[i]
    __shared__ float buf[2][G][4][64];       // [ping-pong][row][state][lane]

    const int tid  = threadIdx.x;
    const int wid  = tid >> 6;
    const int lane = tid & 63;

    for (int i = tid; i < ODE_L - 1; i += TPB) {
        sh_h[i] = s_grid[i + 1] - s_grid[i];
    }

    // Uniform weights -> scalar loads / SGPRs.
    const float w0  = w[0],  w1  = w[1],  w2  = w[2];
    const float w3  = w[3],  w4  = w[4],  w5  = w[5],  w6  = w[6],  w7 = w[7],
                w8  = w[8];
    const float w9  = w[9],  w10 = w[10], w11 = w[11], w12 = w[12],
                w13 = w[13], w14 = w[14];
    const float w15 = w[15], w16 = w[16], w17 = w[17], w18 = w[18],
                w19 = w[19], w20 = w[20];

    const unsigned b = blockIdx.x * 64u + (unsigned)lane;

    sync_lds();   // B0: sh_h visible to all waves

    if (wid == 0) {
        // ---------------- compute wave: registers only ----------------
        float A = y0[0 * ODE_B + b];
        float T = y0[1 * ODE_B + b];
        float N = y0[2 * ODE_B + b];
        float C = y0[3 * ODE_B + b];

        // Groups 0..62: rows 1+8g .. 8+8g into buf[g&1].
        for (unsigned g = 0; g < NGRP - 1; ++g) {
            const int p = (int)(g & 1u);
            #pragma unroll
            for (int j = 0; j < G; ++j) {
                const float h = sh_h[g * G + j];
                ODE_STEP(h);
                buf[p][j][0][lane] = A;
                buf[p][j][1][lane] = T;
                buf[p][j][2][lane] = N;
                buf[p][j][3][lane] = C;
            }
            sync_lds();   // B(g+1)
        }
        // Group 63: rows 505..511 (7 rows) into buf[1].
        #pragma unroll
        for (int j = 0; j < 7; ++j) {
            const float h = sh_h[504 + j];
            ODE_STEP(h);
            buf[1][j][0][lane] = A;
            buf[1][j][1][lane] = T;
            buf[1][j][2][lane] = N;
            buf[1][j][3][lane] = C;
        }
        sync_lds();       // B64
    } else {
        // ---------------- writer waves: LDS -> global streaming ----------------
        const int st = wid - 1;                    // owned state row
        const unsigned ob = (unsigned)st * ODE_B + b;

        // Slot g=0: row 0 is y0 itself (copied straight through).
        out[ob] = y0[ob];
        sync_lds();       // B1

        // Slot g: store group g-1 (rows 1+8(g-1) .. 8+8(g-1)) from buf[(g-1)&1].
        for (unsigned g = 1; g < NGRP; ++g) {
            const int p = (int)((g - 1u) & 1u);
            const unsigned r0 = 1u + (g - 1u) * G;
            #pragma unroll
            for (int j = 0; j < G; ++j) {
                const float v = buf[p][j][st][lane];
                out[(r0 + (unsigned)j) * (4u * ODE_B) + ob] = v;
            }
            sync_lds();   // B(g+1)
        }
        // Final: group 63 (rows 505..511) from buf[1]; no barrier needed after.
        #pragma unroll
        for (int j = 0; j < 7; ++j) {
            const float v = buf[1][j][st][lane];
            out[(505u + (unsigned)j) * (4u * ODE_B) + ob] = v;
        }
    }
}

extern "C" void kernel_launch(void* const* d_in, const int* in_sizes, int n_in,
                              void* d_out, int out_size, void* d_ws, size_t ws_size,
                              hipStream_t stream) {
    (void)in_sizes; (void)n_in; (void)d_ws; (void)ws_size; (void)out_size;

    const float* s_grid = (const float*)d_in[0];
    const float* y0     = (const float*)d_in[1];
    const float* w      = (const float*)d_in[2];
    float* out          = (float*)d_out;

    // 512 blocks x 320 threads (1 compute + 4 writer waves per block).
    population_ode_kernel<<<dim3(ODE_B / 64), dim3(TPB), 0, stream>>>(
        s_grid, y0, w, out);
}

// Round 6
// 265.817 us; speedup vs baseline: 1.0036x; 1.0036x over previous
//
#include <hip/hip_runtime.h>

// PopulationODE: explicit Euler, L=512, B=32768, 4 states, 21 weights.
// Output [L,4,B] fp32 = 256 MiB -> write-bound (harness fill: 6.6 TB/s).
//
// Kernel-only history (dur_us - ~163us harness fill):
//   R0 ~110us, R3 reg-pipe ~102us, R4 producer/consumer ~104us: three
//   structures, same ~2.5 TB/s write ceiling. Common factor: 256 B per-wave
//   write granules scattered at 128KB-512KB strides -> DRAM page thrash.
//   R5 (1 KB granule test) never ran: container died; likely cause was
//   67.5 KB static LDS.
// R6 = R5 hardened: G=4 -> 34 KB LDS. 128 blocks x 512 threads:
//   4 compute waves (64 traj each, registers only, no vmcnt waits) +
//   4 writer waves (one state row each; float4 LDS->global = 1 KB contiguous
//   per wave-store). Sync = lgkmcnt-only barrier (vmcnt never drained in
//   loop -> stores pipeline across group slots). Bit-identical step order.

#define ODE_L 512
#define ODE_B 32768
#define G      4                 // rows per LDS group
#define NGRP   128               // groups 0..126 full (4 rows), group 127 = 3 rows
#define CWAVES 4
#define WWAVES 4
#define TPB    ((CWAVES + WWAVES) * 64)   // 512
#define BB     256               // trajectories per block
#define NBLK   (ODE_B / BB)      // 128

// One Euler step (bit-identical op order to the verified R0/R3/R4 kernels).
#define ODE_STEP(h)                                                          \
  do {                                                                       \
    const float dA = w0  + w1  * A + w2  * A * A;                            \
    const float dT = w3  + w4  * T + w5  * T * T + w6  * A + w7  * A * A +   \
                     w8  * A * T;                                            \
    const float dN = w9  + w10 * N + w11 * N * N + w12 * T + w13 * T * T +   \
                     w14 * T * N;                                            \
    const float dC = w15 + w16 * C + w17 * C * C + w18 * N + w19 * N * N +   \
                     w20 * N * C;                                            \
    A += h * dA; T += h * dT; N += h * dN; C += h * dC;                      \
  } while (0)

// LDS-only barrier: drain DS ops, do NOT drain vmcnt (stores stay in flight).
__device__ __forceinline__ void sync_lds() {
    asm volatile("s_waitcnt lgkmcnt(0)" ::: "memory");
    __builtin_amdgcn_s_barrier();
}

__global__ __launch_bounds__(TPB) void population_ode_kernel(
    const float* __restrict__ s_grid,   // [L]
    const float* __restrict__ y0,       // [4, B]
    const float* __restrict__ w,        // [21]
    float* __restrict__ out)            // [L, 4, B]
{
    __shared__ float sh_h[ODE_L - 1];        // h[i] = s[i+1] - s[i]
    __shared__ float buf[2][G][4][BB];       // [ping-pong][row][state][traj] = 32 KB

    const int tid  = threadIdx.x;
    const int wid  = tid >> 6;
    const int lane = tid & 63;

    for (int i = tid; i < ODE_L - 1; i += TPB) {
        sh_h[i] = s_grid[i + 1] - s_grid[i];
    }

    // Uniform weights -> scalar loads / SGPRs.
    const float w0  = w[0],  w1  = w[1],  w2  = w[2];
    const float w3  = w[3],  w4  = w[4],  w5  = w[5],  w6  = w[6],  w7 = w[7],
                w8  = w[8];
    const float w9  = w[9],  w10 = w[10], w11 = w[11], w12 = w[12],
                w13 = w[13], w14 = w[14];
    const float w15 = w[15], w16 = w[16], w17 = w[17], w18 = w[18],
                w19 = w[19], w20 = w[20];

    sync_lds();   // B0: sh_h visible to all waves

    if (wid < CWAVES) {
        // ---- compute waves: 64 trajectories each, registers only ----
        const int      col = wid * 64 + lane;               // 0..255 within block
        const unsigned b   = blockIdx.x * (unsigned)BB + (unsigned)col;

        float A = y0[0 * ODE_B + b];
        float T = y0[1 * ODE_B + b];
        float N = y0[2 * ODE_B + b];
        float C = y0[3 * ODE_B + b];

        // Groups 0..126: rows 1+4g .. 4+4g into buf[g&1].
        for (unsigned g = 0; g < NGRP - 1; ++g) {
            const int p = (int)(g & 1u);
            #pragma unroll
            for (int j = 0; j < G; ++j) {
                const float h = sh_h[g * G + j];
                ODE_STEP(h);
                buf[p][j][0][col] = A;
                buf[p][j][1][col] = T;
                buf[p][j][2][col] = N;
                buf[p][j][3][col] = C;
            }
            sync_lds();   // B(g+1): 127 barriers
        }
        // Group 127: rows 509..511 (3 rows, h[508..510]) into buf[1].
        #pragma unroll
        for (int j = 0; j < 3; ++j) {
            const float h = sh_h[508 + j];
            ODE_STEP(h);
            buf[1][j][0][col] = A;
            buf[1][j][1][col] = T;
            buf[1][j][2][col] = N;
            buf[1][j][3][col] = C;
        }
        sync_lds();       // B128  (compute total: 129 barriers)
    } else {
        // ---- writer waves: LDS -> global, 1 KB contiguous per wave-store ----
        const int st = wid - CWAVES;                         // owned state row 0..3
        const float4* y4 = reinterpret_cast<const float4*>(y0);
        float4*       o4 = reinterpret_cast<float4*>(out);
        // out float4 index: row * 32768 + st * 8192 + b/4
        const unsigned c4 = blockIdx.x * (unsigned)(BB / 4) + (unsigned)lane;
        const unsigned sb = (unsigned)st * (ODE_B / 4) + c4;

        // Row 0 is y0 itself (float4 passthrough).
        o4[sb] = y4[sb];
        sync_lds();       // B1

        // Slot g: store group g-1 (rows 1+4(g-1) .. 4+4(g-1)) from buf[(g-1)&1].
        for (unsigned g = 1; g < NGRP; ++g) {
            const int p = (int)((g - 1u) & 1u);
            const unsigned r0 = 1u + (g - 1u) * G;
            #pragma unroll
            for (int j = 0; j < G; ++j) {
                const float4 v = *reinterpret_cast<const float4*>(&buf[p][j][st][lane * 4]);
                o4[(r0 + (unsigned)j) * (unsigned)ODE_B + sb] = v;
            }
            sync_lds();   // B2..B128 (writer total: 129 barriers)
        }
        // Final: group 127 (rows 509..511) from buf[1]; no barrier after.
        #pragma unroll
        for (int j = 0; j < 3; ++j) {
            const float4 v = *reinterpret_cast<const float4*>(&buf[1][j][st][lane * 4]);
            o4[(509u + (unsigned)j) * (unsigned)ODE_B + sb] = v;
        }
    }
}

extern "C" void kernel_launch(void* const* d_in, const int* in_sizes, int n_in,
                              void* d_out, int out_size, void* d_ws, size_t ws_size,
                              hipStream_t stream) {
    (void)in_sizes; (void)n_in; (void)d_ws; (void)ws_size; (void)out_size;

    const float* s_grid = (const float*)d_in[0];
    const float* y0     = (const float*)d_in[1];
    const float* w      = (const float*)d_in[2];
    float* out          = (float*)d_out;

    // 128 blocks x 512 threads (4 compute + 4 writer waves, 256 traj/block).
    population_ode_kernel<<<dim3(NBLK), dim3(TPB), 0, stream>>>(
        s_grid, y0, w, out);
}